// Round 10
// baseline (55.297 us; speedup 1.0000x reference)
//
#include <hip/hip_runtime.h>
#include <hip/hip_fp16.h>

// 21-qubit QNN, 3 layers, fused into TWO sweeps via light-cone gate scheduling.
// y bit b <-> qubit 20-b. Sweep A: local window y[0:12] (qubits 8..20), 35 Rots;
// CNOTs folded into LDS-exchange gathers. Sweep B: local window z[0:12]
// (qubits 0..12), 28 Rots; 3 leftover CNOTs folded into block-address perm;
// final-layer CNOTs acting only inside the window are sum-invariant -> skipped.
// z layout: z[0:4]=y[8:12] (asc), z[5:12]=y[13:20], z[13:20]=y[0:7]
// LDS: float2 DOUBLE-buffer (130 KB -- free: grid==256==#CUs so 1 block/CU
// either way), ONE barrier per phase. sweepA's final store issues directly
// from the E11A register layout (regs {e0,e1,e2,e8}) as int2 -- same memory
// transaction count as the old int4 path but one full PHASE cheaper.

union H4 { int4 i4; __half2 h[4]; };
union H2 { int2 i2; __half2 h[2]; };

__device__ __forceinline__ unsigned SWZ(unsigned i) {
    return i ^ ((i >> 4) & 0xFu) ^ ((i >> 8) & 0xFu);   // bank spread, bijective
}
// CNOT fold groups (ctrl bit = tgt bit + 1 in local space): x ^ ((x>>1) & tgtMask).
// f2: mA = LATER-in-time group (applied first in gather), mB = earlier group.
__device__ __forceinline__ unsigned f1(unsigned x, unsigned m) {
    return x ^ ((x >> 1) & m);
}
__device__ __forceinline__ unsigned f2(unsigned x, unsigned mA, unsigned mB) {
    unsigned t = x ^ ((x >> 1) & mA);
    return t ^ ((t >> 1) & mB);
}

__device__ __forceinline__ void crot(const float2 u00, const float2 u01,
                                     const float2 u10, const float2 u11,
                                     float2& a, float2& b) {
    float2 na, nb;
    na.x = u00.x*a.x - u00.y*a.y + u01.x*b.x - u01.y*b.y;
    na.y = u00.x*a.y + u00.y*a.x + u01.x*b.y + u01.y*b.x;
    nb.x = u10.x*a.x - u10.y*a.y + u11.x*b.x - u11.y*b.y;
    nb.y = u10.x*a.y + u10.y*a.x + u11.x*b.y + u11.y*b.x;
    a = na; b = nb;
}

// apply up to 4 Rots; ids = 21*layer+qubit into gU; id k acts on reg-bit k.
__device__ __forceinline__ void apply4(float2 v[16], const float2* gU,
                                       int id0, int id1, int id2, int id3) {
    const int ids[4] = {id0, id1, id2, id3};
#pragma unroll
    for (int kk = 0; kk < 4; ++kk) {
        const int id = ids[kk];
        if (id < 0) continue;
        const float2 u00 = gU[4*id+0], u01 = gU[4*id+1];
        const float2 u10 = gU[4*id+2], u11 = gU[4*id+3];
#pragma unroll
        for (int x = 0; x < 16; ++x)
            if (!(x & (1 << kk)))
                crot(u00, u01, u10, u11, v[x], v[x | (1 << kk)]);
    }
}

__device__ __forceinline__ void prep_gates_lds(const float* __restrict__ param,
                                               float2* gU, unsigned tid) {
    if (tid < 63) {
        float phi = param[3*tid+0], th = param[3*tid+1], om = param[3*tid+2];
        float s, c;   __sincosf(0.5f*th, &s, &c);
        float sp, cp; __sincosf(-0.5f*(phi+om), &sp, &cp);
        float sm, cm; __sincosf( 0.5f*(phi-om), &sm, &cm);
        gU[4*tid+0] = make_float2( cp*c,  sp*c);
        gU[4*tid+1] = make_float2(-cm*s, -sm*s);
        gU[4*tid+2] = make_float2( cm*s, -sm*s);
        gU[4*tid+3] = make_float2( cp*c, -sp*c);
    }
}

// ---- phase index mappings: (tid 9b, reg 4b) -> 13-bit local index e ----
// sweep A (e = y bits 0..12)
__device__ __forceinline__ unsigned E1A (unsigned t, unsigned r){ return (t<<4)|r; }                                   // regs e{0..3}
__device__ __forceinline__ unsigned E2A (unsigned t, unsigned r){ return ((t>>4)<<8)|(r<<4)|(t&15u); }                 // regs e{4..7}
__device__ __forceinline__ unsigned E3A (unsigned t, unsigned r){ return ((t>>8)<<12)|(r<<8)|(t&255u); }               // regs e{8..11}
__device__ __forceinline__ unsigned E4A (unsigned t, unsigned r){                                                      // regs e{7,8,9,12}
    return (t&127u) | (((t>>7)&3u)<<10) | ((r&1u)<<7) | (((r>>1)&1u)<<8) | (((r>>2)&1u)<<9) | (((r>>3)&1u)<<12);
}
__device__ __forceinline__ unsigned E5A (unsigned t, unsigned r){                                                      // regs e{5,6,10,11}
    return (t&31u) | (((t>>5)&7u)<<7) | (((t>>8)&1u)<<12) | ((r&1u)<<5) | (((r>>1)&1u)<<6) | (((r>>2)&1u)<<10) | (((r>>3)&1u)<<11);
}
__device__ __forceinline__ unsigned E6A (unsigned t, unsigned r){ return (t&1u) | (((t>>1)&255u)<<5) | (r<<1); }       // regs e{1..4}
__device__ __forceinline__ unsigned E7A (unsigned t, unsigned r){                                                      // regs e{0,7,8,9}
    return ((t&63u)<<1) | (((t>>6)&7u)<<10) | (r&1u) | (((r>>1)&1u)<<7) | (((r>>2)&1u)<<8) | (((r>>3)&1u)<<9);
}
__device__ __forceinline__ unsigned E8A (unsigned t, unsigned r){ return (t&7u) | (((t>>3)&63u)<<7) | ((r&15u)<<3); }  // regs e{3..6}
__device__ __forceinline__ unsigned E11A(unsigned t, unsigned r){                                                      // regs {e0,e1,e2,e8}
    return (r&7u) | (((r>>3)&1u)<<8) | ((t&15u)<<9) | ((t>>4)<<3);   // t[0:3]->e[9:12], t[4:8]->e[3:7]
}
// sweep B (e = z bits 0..12)
__device__ __forceinline__ unsigned E1B (unsigned t, unsigned r){ return (t&511u) | (r<<9); }                          // regs e{9..12}
__device__ __forceinline__ unsigned E2B (unsigned t, unsigned r){ return (t&31u) | (((t>>5)&15u)<<9) | (r<<5); }       // regs e{5..8}
__device__ __forceinline__ unsigned E5B (unsigned t, unsigned r){                                                      // regs e{4,10,11,12}
    return (t&15u) | (((t>>4)&31u)<<5) | ((r&1u)<<4) | (((r>>1)&1u)<<10) | (((r>>2)&1u)<<11) | (((r>>3)&1u)<<12);
}
__device__ __forceinline__ unsigned E6B (unsigned t, unsigned r){ return (t&63u) | (((t>>6)&7u)<<10) | (r<<6); }       // regs e{6..9}
__device__ __forceinline__ unsigned E7B (unsigned t, unsigned r){ return (t&3u) | (((t>>2)&127u)<<6) | (r<<2); }       // regs e{2..5}

// one phase: write current mapping to BUF, barrier, read next mapping from BUF.
// NO trailing barrier: next phase writes the OTHER buffer.
#define PHASE(BUF, EW, ER) do { \
    _Pragma("unroll") for (int r = 0; r < 16; ++r) { unsigned e_ = (EW); BUF[SWZ(e_)] = v[r]; } \
    __syncthreads(); \
    _Pragma("unroll") for (int r = 0; r < 16; ++r) { unsigned e_ = (ER); v[r] = BUF[SWZ(e_)]; } \
    } while (0)

__global__ __launch_bounds__(512, 2) void sweepA(const float* __restrict__ feat,
                                                 const float* __restrict__ param,
                                                 __half2* __restrict__ zbuf,
                                                 float* __restrict__ out) {
    __shared__ float2 sh0[8192];
    __shared__ float2 sh1[8192];
    __shared__ float2 gU[252];
    const unsigned tid = threadIdx.x;
    const unsigned F = blockIdx.x;                 // y bits 13..20
    if (F == 0 && tid == 0) out[0] = 0.0f;

    // issue feat loads FIRST; sincos gate prep overlaps the HBM latency
    float4 fraw[4];
    {
        const float4* fp = (const float4*)(feat + (((size_t)F) << 13) + (tid << 4));
#pragma unroll
        for (int c = 0; c < 4; ++c) fraw[c] = fp[c];
    }
    prep_gates_lds(param, gU, tid);

    float2 v[16];
#pragma unroll
    for (int c = 0; c < 4; ++c) {                  // regs = y{0..3}
        v[4*c+0] = make_float2(fraw[c].x, 0.f); v[4*c+1] = make_float2(fraw[c].y, 0.f);
        v[4*c+2] = make_float2(fraw[c].z, 0.f); v[4*c+3] = make_float2(fraw[c].w, 0.f);
    }
    __syncthreads();                                // gU ready
    apply4(v, gU, 20, 19, 18, 17);                  // R0 q20,q19,q18,q17
    PHASE(sh0, E1A(tid,r), E2A(tid,r));
    apply4(v, gU, 16, 15, 14, 13);                  // R0 q16..q13
    PHASE(sh1, E2A(tid,r), E3A(tid,r));
    apply4(v, gU, 12, 11, 10, 9);                   // R0 q12..q9
    // fold: O0{(11,12)..(19,20)} later, E0{(10,11)..(18,19)} earlier
    PHASE(sh0, E3A(tid,r), f2(E4A(tid,r), 0x155u, 0x2AAu));
    apply4(v, gU, 34, 33, 32, 8);                   // R1 q13,q12,q11 ; R0 q8
    // fold: O0(9,10) later, E0(8,9) earlier
    PHASE(sh1, E4A(tid,r), f2(E5A(tid,r), 0x400u, 0x800u));
    apply4(v, gU, 36, 35, 31, 30);                  // R1 q15,q14,q10,q9
    // fold: O1{(11,12),(13,14)} later, E1{(10,11),(12,13),(14,15)} earlier
    PHASE(sh0, E5A(tid,r), f2(E6A(tid,r), 0x140u, 0x2A0u));
    apply4(v, gU, 40, 39, 38, 37);                  // R1 q19,q18,q17,q16
    // fold: O1{(15,16),(17,18)} later, E1{(16,17),(18,19)} earlier
    PHASE(sh1, E6A(tid,r), f2(E7A(tid,r), 0x014u, 0x00Au));
    apply4(v, gU, 41, 55, 54, 53);                  // R1 q20 ; R2 q13,q12,q11
    // fold: O1(19,20) + E2(12,13)  (disjoint bits)
    PHASE(sh0, E7A(tid,r), f1(E8A(tid,r), 0x081u));
    apply4(v, gU, 59, 58, 57, 56);                  // R2 q17,q16,q15,q14
    // fold: O2{(13,14),(15,16)} later, E2{(14,15),(16,17)} earlier
    // read directly into the STORE-ready layout (regs {e0,e1,e2,e8})
    PHASE(sh1, E8A(tid,r), f2(E11A(tid,r), 0x050u, 0x028u));
    apply4(v, gU, 62, 61, 60, -1);                  // R2 q20,q19,q18 on e0,e1,e2; e8 spectator
    // leftover E2(18,19), O2(17,18),(19,20) -> folded into sweepB block perm

    {   // direct int2 store; z layout identical to before:
        // z0=e8 (in-reg), z[1:4]=e[9:12]=tid&15, z[5:12]=F, z[13:15]=e[0:2]=g, z[16:20]=e[3:7]=tid>>4
        int2* zb2 = (int2*)zbuf;
        const unsigned sbase = (tid & 15u) | (F << 4) | ((tid >> 4) << 15);  // int2 units
#pragma unroll
        for (unsigned g = 0; g < 8; ++g) {
            H2 y;
            y.h[0] = __float22half2_rn(v[g]);        // e8 = 0
            y.h[1] = __float22half2_rn(v[g | 8u]);   // e8 = 1
            zb2[sbase | (g << 12)] = y.i2;
        }
    }
}

__global__ __launch_bounds__(512, 2) void sweepB(const __half2* __restrict__ zbuf,
                                                 const float* __restrict__ param,
                                                 float* __restrict__ out) {
    __shared__ float2 sh0[8192];
    __shared__ float2 sh1[8192];
    __shared__ float2 gU[252];
    __shared__ float wsum[8];
    const unsigned tid = threadIdx.x;
    const unsigned B = blockIdx.x * 2u;            // z bits 13..20 = y[0:7]; y0=0 only

    // sweepA-leftover fold on block bits: O2{y1->y0, y3->y2} later, E2{y2->y1} earlier
    unsigned t0 = B ^ ((B >> 1) & 5u);
    const unsigned Bp = t0 ^ ((t0 >> 1) & 2u);
    // issue zbuf loads FIRST; sincos gate prep overlaps the HBM latency
    H4 x[4];
    {
        const int4* src = (const int4*)(zbuf + (((size_t)Bp) << 13));
#pragma unroll
        for (unsigned c = 0; c < 4; ++c) x[c].i4 = src[c * 512 + tid];
    }
    prep_gates_lds(param, gU, tid);
#pragma unroll
    for (unsigned c = 0; c < 4; ++c) {
        unsigned e = (c << 11) | (tid << 2);
        sh0[SWZ(e)]     = __half22float2(x[c].h[0]);
        sh0[SWZ(e | 1)] = __half22float2(x[c].h[1]);
        sh0[SWZ(e | 2)] = __half22float2(x[c].h[2]);
        sh0[SWZ(e | 3)] = __half22float2(x[c].h[3]);
    }
    __syncthreads();                                // gU + tile ready

    float2 v[16];
#pragma unroll
    for (int r = 0; r < 16; ++r) v[r] = sh0[SWZ(E1B(tid,(unsigned)r))];
    apply4(v, gU, 3, 2, 1, 0);                      // R0 q3,q2,q1,q0
    // fold: E0{(0,1),(2,3)} -> tgt e-bits {11,9}
    PHASE(sh1, E1B(tid,r), f1(E2B(tid,r), 0xA00u));
    apply4(v, gU, 7, 6, 5, 4);                      // R0 q7..q4
    // fold: O0{(1,2),(3,4),(5,6),(7,8)} later, E0{(4,5),(6,7)} earlier
    PHASE(sh0, E2B(tid,r), f2(E1B(tid,r), 0x550u, 0x0A0u));
    apply4(v, gU, 24, 23, 22, 21);                  // R1 q3..q0
    // fold: E1{(0,1),(2,3)}
    PHASE(sh1, E1B(tid,r), f1(E2B(tid,r), 0xA00u));
    apply4(v, gU, 28, 27, 26, 25);                  // R1 q7..q4
    // fold: O1{(1,2),(3,4),(5,6)} later, E1{(4,5),(6,7)} earlier
    PHASE(sh0, E2B(tid,r), f2(E5B(tid,r), 0x540u, 0x0A0u));
    apply4(v, gU, 29, 44, 43, 42);                  // R1 q8 ; R2 q2,q1,q0
    // fold: O1{(7,8),(9,10)} later, E1(8,9) earlier
    PHASE(sh1, E5B(tid,r), f2(E6B(tid,r), 0x014u, 0x008u));
    apply4(v, gU, 48, 47, 46, 45);                  // R2 q6,q5,q4,q3
    PHASE(sh0, E6B(tid,r), E7B(tid,r));             // no fold
    apply4(v, gU, 52, 51, 50, 49);                  // R2 q10,q9,q8,q7
    // final E2/O2 inside window: local perms not touching y0 -> sum-invariant, skip
    float acc = 0.f;
#pragma unroll
    for (int r = 0; r < 16; ++r) acc += v[r].x*v[r].x + v[r].y*v[r].y;
    for (int off = 32; off; off >>= 1) acc += __shfl_down(acc, off);
    if ((tid & 63u) == 0) wsum[tid >> 6] = acc;
    __syncthreads();
    if (tid == 0) {
        float s = 0.f;
#pragma unroll
        for (int w = 0; w < 8; ++w) s += wsum[w];
        atomicAdd(out, s);
    }
}

extern "C" void kernel_launch(void* const* d_in, const int* in_sizes, int n_in,
                              void* d_out, int out_size, void* d_ws, size_t ws_size,
                              hipStream_t stream) {
    const float* feat  = (const float*)d_in[0];
    const float* param = (const float*)d_in[1];
    float* out = (float*)d_out;
    __half2* zbuf = (__half2*)d_ws;                // 2^21 * 4B = 8 MB

    sweepA<<<256, 512, 0, stream>>>(feat, param, zbuf, out);
    sweepB<<<128, 512, 0, stream>>>(zbuf, param, out);
}

// Round 11
// 46.037 us; speedup vs baseline: 1.2011x; 1.2011x over previous
//
#include <hip/hip_runtime.h>
#include <hip/hip_fp16.h>

// 21-qubit QNN, 3 layers, fused into TWO sweeps via light-cone gate scheduling.
// y bit b <-> qubit 20-b. Sweep A: local window y[0:12] (qubits 8..20), 35 Rots;
// CNOTs folded into LDS-exchange gathers. Sweep B: local window z[0:12]
// (qubits 0..12), 28 Rots; 3 leftover CNOTs folded into block-address perm;
// final-layer CNOTs acting only inside the window are sum-invariant -> skipped.
// z layout: z[0:4]=y[8:12] (asc), z[5:12]=y[13:20], z[13:20]=y[0:7]
// This round: complex math on ext_vector float2 so LLVM emits packed-FP32
// (v_pk_fma_f32) -- 8 pk inst/pair vs 16 scalar. crot arithmetic order per
// component is unchanged (bit-identical result).

typedef __attribute__((ext_vector_type(2))) float f2;

union H4 { int4 i4; __half2 h[4]; };
union H2 { int2 i2; __half2 h[2]; };

__device__ __forceinline__ f2 mkf2(float a, float b) { f2 r; r.x = a; r.y = b; return r; }

__device__ __forceinline__ unsigned SWZ(unsigned i) {
    return i ^ ((i >> 4) & 0xFu) ^ ((i >> 8) & 0xFu);   // bank spread, bijective
}
// CNOT fold groups (ctrl bit = tgt bit + 1 in local space): x ^ ((x>>1) & tgtMask).
// f2fold: mA = LATER-in-time group (applied first in gather), mB = earlier group.
__device__ __forceinline__ unsigned f1(unsigned x, unsigned m) {
    return x ^ ((x >> 1) & m);
}
__device__ __forceinline__ unsigned f2fold(unsigned x, unsigned mA, unsigned mB) {
    unsigned t = x ^ ((x >> 1) & mA);
    return t ^ ((t >> 1) & mB);
}

// packed complex rotation: na = u00*a + u01*b ; nb = u10*a + u11*b
// cmul(u,z) = u.x*z + u.y*sw(z), sw(z) = (-z.y, z.x)  -> pk_mul + pk_fma chains
__device__ __forceinline__ void crot(const f2 u00, const f2 u01,
                                     const f2 u10, const f2 u11,
                                     f2& a, f2& b) {
    const f2 sa = mkf2(-a.y, a.x);
    const f2 sb = mkf2(-b.y, b.x);
    f2 na = u00.x * a;
    na += u00.y * sa;
    na += u01.x * b;
    na += u01.y * sb;
    f2 nb = u10.x * a;
    nb += u10.y * sa;
    nb += u11.x * b;
    nb += u11.y * sb;
    a = na; b = nb;
}

// apply up to 4 Rots; ids = 21*layer+qubit into gU; id k acts on reg-bit k.
__device__ __forceinline__ void apply4(f2 v[16], const f2* gU,
                                       int id0, int id1, int id2, int id3) {
    const int ids[4] = {id0, id1, id2, id3};
#pragma unroll
    for (int kk = 0; kk < 4; ++kk) {
        const int id = ids[kk];
        if (id < 0) continue;
        const f2 u00 = gU[4*id+0], u01 = gU[4*id+1];
        const f2 u10 = gU[4*id+2], u11 = gU[4*id+3];
#pragma unroll
        for (int x = 0; x < 16; ++x)
            if (!(x & (1 << kk)))
                crot(u00, u01, u10, u11, v[x], v[x | (1 << kk)]);
    }
}

__device__ __forceinline__ void prep_gates_lds(const float* __restrict__ param,
                                               f2* gU, unsigned tid) {
    if (tid < 63) {
        float phi = param[3*tid+0], th = param[3*tid+1], om = param[3*tid+2];
        float s, c;   __sincosf(0.5f*th, &s, &c);
        float sp, cp; __sincosf(-0.5f*(phi+om), &sp, &cp);
        float sm, cm; __sincosf( 0.5f*(phi-om), &sm, &cm);
        gU[4*tid+0] = mkf2( cp*c,  sp*c);
        gU[4*tid+1] = mkf2(-cm*s, -sm*s);
        gU[4*tid+2] = mkf2( cm*s, -sm*s);
        gU[4*tid+3] = mkf2( cp*c, -sp*c);
    }
}

// ---- phase index mappings: (tid 9b, reg 4b) -> 13-bit local index e ----
// sweep A (e = y bits 0..12)
__device__ __forceinline__ unsigned E1A (unsigned t, unsigned r){ return (t<<4)|r; }                                   // regs e{0..3}
__device__ __forceinline__ unsigned E2A (unsigned t, unsigned r){ return ((t>>4)<<8)|(r<<4)|(t&15u); }                 // regs e{4..7}
__device__ __forceinline__ unsigned E3A (unsigned t, unsigned r){ return ((t>>8)<<12)|(r<<8)|(t&255u); }               // regs e{8..11}
__device__ __forceinline__ unsigned E4A (unsigned t, unsigned r){                                                      // regs e{7,8,9,12}
    return (t&127u) | (((t>>7)&3u)<<10) | ((r&1u)<<7) | (((r>>1)&1u)<<8) | (((r>>2)&1u)<<9) | (((r>>3)&1u)<<12);
}
__device__ __forceinline__ unsigned E5A (unsigned t, unsigned r){                                                      // regs e{5,6,10,11}
    return (t&31u) | (((t>>5)&7u)<<7) | (((t>>8)&1u)<<12) | ((r&1u)<<5) | (((r>>1)&1u)<<6) | (((r>>2)&1u)<<10) | (((r>>3)&1u)<<11);
}
__device__ __forceinline__ unsigned E6A (unsigned t, unsigned r){ return (t&1u) | (((t>>1)&255u)<<5) | (r<<1); }       // regs e{1..4}
__device__ __forceinline__ unsigned E7A (unsigned t, unsigned r){                                                      // regs e{0,7,8,9}
    return ((t&63u)<<1) | (((t>>6)&7u)<<10) | (r&1u) | (((r>>1)&1u)<<7) | (((r>>2)&1u)<<8) | (((r>>3)&1u)<<9);
}
__device__ __forceinline__ unsigned E8A (unsigned t, unsigned r){ return (t&7u) | (((t>>3)&63u)<<7) | ((r&15u)<<3); }  // regs e{3..6}
__device__ __forceinline__ unsigned E11A(unsigned t, unsigned r){                                                      // regs {e0,e1,e2,e8}
    return (r&7u) | (((r>>3)&1u)<<8) | ((t&15u)<<9) | ((t>>4)<<3);   // t[0:3]->e[9:12], t[4:8]->e[3:7]
}
// sweep B (e = z bits 0..12)
__device__ __forceinline__ unsigned E1B (unsigned t, unsigned r){ return (t&511u) | (r<<9); }                          // regs e{9..12}
__device__ __forceinline__ unsigned E2B (unsigned t, unsigned r){ return (t&31u) | (((t>>5)&15u)<<9) | (r<<5); }       // regs e{5..8}
__device__ __forceinline__ unsigned E5B (unsigned t, unsigned r){                                                      // regs e{4,10,11,12}
    return (t&15u) | (((t>>4)&31u)<<5) | ((r&1u)<<4) | (((r>>1)&1u)<<10) | (((r>>2)&1u)<<11) | (((r>>3)&1u)<<12);
}
__device__ __forceinline__ unsigned E6B (unsigned t, unsigned r){ return (t&63u) | (((t>>6)&7u)<<10) | (r<<6); }       // regs e{6..9}
__device__ __forceinline__ unsigned E7B (unsigned t, unsigned r){ return (t&3u) | (((t>>2)&127u)<<6) | (r<<2); }       // regs e{2..5}

// one phase: write current mapping to BUF, barrier, read next mapping from BUF.
// NO trailing barrier: next phase writes the OTHER buffer.
#define PHASE(BUF, EW, ER) do { \
    _Pragma("unroll") for (int r = 0; r < 16; ++r) { unsigned e_ = (EW); BUF[SWZ(e_)] = v[r]; } \
    __syncthreads(); \
    _Pragma("unroll") for (int r = 0; r < 16; ++r) { unsigned e_ = (ER); v[r] = BUF[SWZ(e_)]; } \
    } while (0)

__global__ __launch_bounds__(512, 2) void sweepA(const float* __restrict__ feat,
                                                 const float* __restrict__ param,
                                                 __half2* __restrict__ zbuf,
                                                 float* __restrict__ out) {
    __shared__ f2 sh0[8192];
    __shared__ f2 sh1[8192];
    __shared__ f2 gU[252];
    const unsigned tid = threadIdx.x;
    const unsigned F = blockIdx.x;                 // y bits 13..20
    if (F == 0 && tid == 0) out[0] = 0.0f;

    // issue feat loads FIRST; sincos gate prep overlaps the HBM latency
    float4 fraw[4];
    {
        const float4* fp = (const float4*)(feat + (((size_t)F) << 13) + (tid << 4));
#pragma unroll
        for (int c = 0; c < 4; ++c) fraw[c] = fp[c];
    }
    prep_gates_lds(param, gU, tid);

    f2 v[16];
#pragma unroll
    for (int c = 0; c < 4; ++c) {                  // regs = y{0..3}
        v[4*c+0] = mkf2(fraw[c].x, 0.f); v[4*c+1] = mkf2(fraw[c].y, 0.f);
        v[4*c+2] = mkf2(fraw[c].z, 0.f); v[4*c+3] = mkf2(fraw[c].w, 0.f);
    }
    __syncthreads();                                // gU ready
    apply4(v, gU, 20, 19, 18, 17);                  // R0 q20,q19,q18,q17
    PHASE(sh0, E1A(tid,r), E2A(tid,r));
    apply4(v, gU, 16, 15, 14, 13);                  // R0 q16..q13
    PHASE(sh1, E2A(tid,r), E3A(tid,r));
    apply4(v, gU, 12, 11, 10, 9);                   // R0 q12..q9
    // fold: O0{(11,12)..(19,20)} later, E0{(10,11)..(18,19)} earlier
    PHASE(sh0, E3A(tid,r), f2fold(E4A(tid,r), 0x155u, 0x2AAu));
    apply4(v, gU, 34, 33, 32, 8);                   // R1 q13,q12,q11 ; R0 q8
    // fold: O0(9,10) later, E0(8,9) earlier
    PHASE(sh1, E4A(tid,r), f2fold(E5A(tid,r), 0x400u, 0x800u));
    apply4(v, gU, 36, 35, 31, 30);                  // R1 q15,q14,q10,q9
    // fold: O1{(11,12),(13,14)} later, E1{(10,11),(12,13),(14,15)} earlier
    PHASE(sh0, E5A(tid,r), f2fold(E6A(tid,r), 0x140u, 0x2A0u));
    apply4(v, gU, 40, 39, 38, 37);                  // R1 q19,q18,q17,q16
    // fold: O1{(15,16),(17,18)} later, E1{(16,17),(18,19)} earlier
    PHASE(sh1, E6A(tid,r), f2fold(E7A(tid,r), 0x014u, 0x00Au));
    apply4(v, gU, 41, 55, 54, 53);                  // R1 q20 ; R2 q13,q12,q11
    // fold: O1(19,20) + E2(12,13)  (disjoint bits)
    PHASE(sh0, E7A(tid,r), f1(E8A(tid,r), 0x081u));
    apply4(v, gU, 59, 58, 57, 56);                  // R2 q17,q16,q15,q14
    // fold: O2{(13,14),(15,16)} later, E2{(14,15),(16,17)} earlier
    // read directly into the STORE-ready layout (regs {e0,e1,e2,e8})
    PHASE(sh1, E8A(tid,r), f2fold(E11A(tid,r), 0x050u, 0x028u));
    apply4(v, gU, 62, 61, 60, -1);                  // R2 q20,q19,q18 on e0,e1,e2; e8 spectator
    // leftover E2(18,19), O2(17,18),(19,20) -> folded into sweepB block perm

    {   // direct int2 store; z layout identical to before:
        // z0=e8 (in-reg), z[1:4]=e[9:12]=tid&15, z[5:12]=F, z[13:15]=e[0:2]=g, z[16:20]=e[3:7]=tid>>4
        int2* zb2 = (int2*)zbuf;
        const unsigned sbase = (tid & 15u) | (F << 4) | ((tid >> 4) << 15);  // int2 units
#pragma unroll
        for (unsigned g = 0; g < 8; ++g) {
            H2 y;
            y.h[0] = __float22half2_rn(make_float2(v[g].x,      v[g].y));        // e8 = 0
            y.h[1] = __float22half2_rn(make_float2(v[g | 8u].x, v[g | 8u].y));   // e8 = 1
            zb2[sbase | (g << 12)] = y.i2;
        }
    }
}

__global__ __launch_bounds__(512, 2) void sweepB(const __half2* __restrict__ zbuf,
                                                 const float* __restrict__ param,
                                                 float* __restrict__ out) {
    __shared__ f2 sh0[8192];
    __shared__ f2 sh1[8192];
    __shared__ f2 gU[252];
    __shared__ float wsum[8];
    const unsigned tid = threadIdx.x;
    const unsigned B = blockIdx.x * 2u;            // z bits 13..20 = y[0:7]; y0=0 only

    // sweepA-leftover fold on block bits: O2{y1->y0, y3->y2} later, E2{y2->y1} earlier
    unsigned t0 = B ^ ((B >> 1) & 5u);
    const unsigned Bp = t0 ^ ((t0 >> 1) & 2u);
    // issue zbuf loads FIRST; sincos gate prep overlaps the HBM latency
    H4 x[4];
    {
        const int4* src = (const int4*)(zbuf + (((size_t)Bp) << 13));
#pragma unroll
        for (unsigned c = 0; c < 4; ++c) x[c].i4 = src[c * 512 + tid];
    }
    prep_gates_lds(param, gU, tid);
#pragma unroll
    for (unsigned c = 0; c < 4; ++c) {
        unsigned e = (c << 11) | (tid << 2);
#pragma unroll
        for (unsigned k = 0; k < 4; ++k) {
            float2 t = __half22float2(x[c].h[k]);
            sh0[SWZ(e | k)] = mkf2(t.x, t.y);
        }
    }
    __syncthreads();                                // gU + tile ready

    f2 v[16];
#pragma unroll
    for (int r = 0; r < 16; ++r) v[r] = sh0[SWZ(E1B(tid,(unsigned)r))];
    apply4(v, gU, 3, 2, 1, 0);                      // R0 q3,q2,q1,q0
    // fold: E0{(0,1),(2,3)} -> tgt e-bits {11,9}
    PHASE(sh1, E1B(tid,r), f1(E2B(tid,r), 0xA00u));
    apply4(v, gU, 7, 6, 5, 4);                      // R0 q7..q4
    // fold: O0{(1,2),(3,4),(5,6),(7,8)} later, E0{(4,5),(6,7)} earlier
    PHASE(sh0, E2B(tid,r), f2fold(E1B(tid,r), 0x550u, 0x0A0u));
    apply4(v, gU, 24, 23, 22, 21);                  // R1 q3..q0
    // fold: E1{(0,1),(2,3)}
    PHASE(sh1, E1B(tid,r), f1(E2B(tid,r), 0xA00u));
    apply4(v, gU, 28, 27, 26, 25);                  // R1 q7..q4
    // fold: O1{(1,2),(3,4),(5,6)} later, E1{(4,5),(6,7)} earlier
    PHASE(sh0, E2B(tid,r), f2fold(E5B(tid,r), 0x540u, 0x0A0u));
    apply4(v, gU, 29, 44, 43, 42);                  // R1 q8 ; R2 q2,q1,q0
    // fold: O1{(7,8),(9,10)} later, E1(8,9) earlier
    PHASE(sh1, E5B(tid,r), f2fold(E6B(tid,r), 0x014u, 0x008u));
    apply4(v, gU, 48, 47, 46, 45);                  // R2 q6,q5,q4,q3
    PHASE(sh0, E6B(tid,r), E7B(tid,r));             // no fold
    apply4(v, gU, 52, 51, 50, 49);                  // R2 q10,q9,q8,q7
    // final E2/O2 inside window: local perms not touching y0 -> sum-invariant, skip
    float acc = 0.f;
#pragma unroll
    for (int r = 0; r < 16; ++r) acc += v[r].x*v[r].x + v[r].y*v[r].y;
    for (int off = 32; off; off >>= 1) acc += __shfl_down(acc, off);
    if ((tid & 63u) == 0) wsum[tid >> 6] = acc;
    __syncthreads();
    if (tid == 0) {
        float s = 0.f;
#pragma unroll
        for (int w = 0; w < 8; ++w) s += wsum[w];
        atomicAdd(out, s);
    }
}

extern "C" void kernel_launch(void* const* d_in, const int* in_sizes, int n_in,
                              void* d_out, int out_size, void* d_ws, size_t ws_size,
                              hipStream_t stream) {
    const float* feat  = (const float*)d_in[0];
    const float* param = (const float*)d_in[1];
    float* out = (float*)d_out;
    __half2* zbuf = (__half2*)d_ws;                // 2^21 * 4B = 8 MB

    sweepA<<<256, 512, 0, stream>>>(feat, param, zbuf, out);
    sweepB<<<128, 512, 0, stream>>>(zbuf, param, out);
}